// Round 13
// baseline (65.001 us; speedup 1.0000x reference)
//
#include <hip/hip_runtime.h>

// RoiPoolingConv: fm [64,64,1024] f32 NHWC, rois [300,4] int32 (x,y,w,h),
// out [300,14,14,1024] f32.
//
// FINAL CONFIG (empirical best, R10 = 52.9 us):
//  1. sort_items: counting-sort 4200 (roi,py) items by y0 into perm (d_ws).
//  2. roi_pool_cache_kernel: one block per item, 256 threads x float4 over
//     1024 channels, loop px. y0-sorted + bijective XCD swizzle (per-XCD L2
//     read locality). Plain per-px stores (NT stores: -6.5us, R8; NT loads:
//     -67us, R6). Monotone 2-column register cache with wave-uniform scalar
//     guards (R10: +1.1us).
// Structural roofline: 241 MB compulsory writes / 6.9 TB/s calibrated
// pure-store rate = 35 us; mixed read/write coexistence in L2/fabric adds
// ~1.4x, unresponsive to read-volume (x0.5), transactions (x0.55), latency
// pipelining, occupancy (x2), and cache-hint interventions (R4-R12).

#define POOL 14
#define FMW 64
#define CH 1024
#define C4 (CH / 4)        // 256 float4 per pixel
#define MAX_ITEMS (300 * POOL)

typedef float f4 __attribute__((ext_vector_type(4)));

__global__ __launch_bounds__(1024) void sort_items_kernel(
    const int* __restrict__ rois, int num_rois, int* __restrict__ perm)
{
    __shared__ int   base[64];
    __shared__ short s_y0[MAX_ITEMS];
    __shared__ int   s_yh[600];          // (y,h) per roi
    const int tid = threadIdx.x;
    const int num_items = num_rois * POOL;

    if (tid < 64) base[tid] = 0;
    for (int i = tid; i < num_rois; i += blockDim.x) {
        s_yh[i * 2]     = rois[i * 4 + 1];
        s_yh[i * 2 + 1] = rois[i * 4 + 3];
    }
    __syncthreads();

    for (int i = tid; i < num_items; i += blockDim.x) {
        const int roi = i / POOL, py = i % POOL;
        const int y = s_yh[roi * 2], h = s_yh[roi * 2 + 1];
        const float fy = (float)y + (float)py * ((float)h * (1.0f / 14.0f));
        const int y0 = (int)floorf(fy) & 63;
        s_y0[i] = (short)y0;
        atomicAdd(&base[y0], 1);
    }
    __syncthreads();

    if (tid < 64) {
        const int orig = base[tid];
        int v = orig;
        #pragma unroll
        for (int d = 1; d < 64; d <<= 1) {
            const int t = __shfl_up(v, d, 64);
            if (tid >= d) v += t;
        }
        base[tid] = v - orig;
    }
    __syncthreads();

    for (int i = tid; i < num_items; i += blockDim.x) {
        const int pos = atomicAdd(&base[(int)s_y0[i]], 1);
        perm[pos] = i;
    }
}

__global__ __launch_bounds__(256) void roi_pool_cache_kernel(
    const float* __restrict__ fm,
    const int* __restrict__ rois,
    const int* __restrict__ perm,
    int nw,
    float* __restrict__ out)
{
    // bijective XCD swizzle (nw % 8 == 0): XCD j gets a contiguous y0 band
    const int per = nw >> 3;
    const int b   = blockIdx.x;
    const int sb  = (b & 7) * per + (b >> 3);
    const int item = __builtin_amdgcn_readfirstlane(perm[sb]);

    const int py  = item % POOL;
    const int roi = item / POOL;

    const int4 r = *reinterpret_cast<const int4*>(rois + roi * 4);
    const int x = __builtin_amdgcn_readfirstlane(r.x);
    const int y = __builtin_amdgcn_readfirstlane(r.y);
    const int w = __builtin_amdgcn_readfirstlane(r.z);
    const int h = __builtin_amdgcn_readfirstlane(r.w);

    // Legacy-TF bilinear (align_corners=False, no half-pixel centers)
    const float fy = (float)y + (float)py * ((float)h * (1.0f / 14.0f));
    const int   y0 = __builtin_amdgcn_readfirstlane((int)floorf(fy));
    const int   y1 = min(y0 + 1, y + h - 1);
    const float wy = fy - (float)y0;

    const int c = threadIdx.x;  // float4 lane over channels
    const f4* row0 = reinterpret_cast<const f4*>(fm) + (size_t)(y0 * FMW) * C4 + c;
    const f4* row1 = reinterpret_cast<const f4*>(fm) + (size_t)(y1 * FMW) * C4 + c;
    f4* op = reinterpret_cast<f4*>(out) + (size_t)((roi * POOL + py) * POOL) * C4 + c;

    const float wscale = (float)w * (1.0f / 14.0f);
    const int   xmax   = x + w - 1;

    // 2-column register cache. Invariant: c1 == min(c0 + 1, xmax);
    // (tl,bl) hold column c0, (tr,br) hold column c1.
    int c0 = x;
    int c1 = min(x + 1, xmax);
    f4 tl = row0[(size_t)c0 * C4];
    f4 bl = row1[(size_t)c0 * C4];
    f4 tr, br;
    if (c1 != c0) { tr = row0[(size_t)c1 * C4]; br = row1[(size_t)c1 * C4]; }
    else          { tr = tl; br = bl; }

    for (int px = 0; px < POOL; ++px) {
        const float fx = (float)x + (float)px * wscale;
        const int   x0 = __builtin_amdgcn_readfirstlane((int)floorf(fx));
        const int   x1 = min(x0 + 1, xmax);
        const float wx = fx - (float)x0;

        if (x0 != c0) {
            if (x0 == c1) { tl = tr; bl = br; }       // shift left by one
            else { tl = row0[(size_t)x0 * C4]; bl = row1[(size_t)x0 * C4]; }
            c0 = x0;
            if (x1 != c1) {
                if (x1 == c0) { tr = tl; br = bl; }   // clamped at xmax
                else { tr = row0[(size_t)x1 * C4]; br = row1[(size_t)x1 * C4]; }
                c1 = x1;
            }
        }
        // else: x1 == min(x0+1,xmax) == c1 by invariant; cache fully valid

        const f4 top = tl + wx * (tr - tl);
        const f4 bot = bl + wx * (br - bl);
        const f4 o   = top + wy * (bot - top);
        op[(size_t)px * C4] = o;                      // plain streaming store
    }
}

// Fallback without permutation (identity order).
__global__ __launch_bounds__(256) void roi_pool_row_kernel_noperm(
    const float* __restrict__ fm,
    const int* __restrict__ rois,
    int nw,
    float* __restrict__ out)
{
    const int sb  = blockIdx.x;
    const int py  = sb % POOL;
    const int roi = sb / POOL;

    const int4 r = *reinterpret_cast<const int4*>(rois + roi * 4);
    const int x = r.x, y = r.y, w = r.z, h = r.w;

    const float fy = (float)y + (float)py * ((float)h * (1.0f / 14.0f));
    const int   y0 = (int)floorf(fy);
    const int   y1 = min(y0 + 1, y + h - 1);
    const float wy = fy - (float)y0;

    const int c = threadIdx.x;
    const f4* row0 = reinterpret_cast<const f4*>(fm) + (size_t)(y0 * FMW) * C4 + c;
    const f4* row1 = reinterpret_cast<const f4*>(fm) + (size_t)(y1 * FMW) * C4 + c;
    f4* op = reinterpret_cast<f4*>(out) + (size_t)((roi * POOL + py) * POOL) * C4 + c;

    const float wscale = (float)w * (1.0f / 14.0f);
    const int   xmax   = x + w - 1;

    for (int px = 0; px < POOL; ++px) {
        const float fx = (float)x + (float)px * wscale;
        const int   x0 = (int)floorf(fx);
        const int   x1 = min(x0 + 1, xmax);
        const float wx = fx - (float)x0;

        const f4 tl = row0[(size_t)x0 * C4];
        const f4 tr = row0[(size_t)x1 * C4];
        const f4 bl = row1[(size_t)x0 * C4];
        const f4 br = row1[(size_t)x1 * C4];

        const f4 top = tl + wx * (tr - tl);
        const f4 bot = bl + wx * (br - bl);
        const f4 o   = top + wy * (bot - top);

        op[(size_t)px * C4] = o;
    }
}

extern "C" void kernel_launch(void* const* d_in, const int* in_sizes, int n_in,
                              void* d_out, int out_size, void* d_ws, size_t ws_size,
                              hipStream_t stream) {
    const float* fm  = (const float*)d_in[0];   // [1,64,64,1024] f32
    const int* rois  = (const int*)d_in[1];     // [1,300,4] i32
    float* out       = (float*)d_out;           // [1,300,14,14,1024] f32

    const int num_rois = in_sizes[1] / 4;       // 300
    const int nw = num_rois * POOL;             // 4200 work items

    if (ws_size >= (size_t)nw * sizeof(int) && (nw & 7) == 0 && nw <= MAX_ITEMS) {
        int* perm = (int*)d_ws;
        sort_items_kernel<<<1, 1024, 0, stream>>>(rois, num_rois, perm);
        roi_pool_cache_kernel<<<nw, 256, 0, stream>>>(fm, rois, perm, nw, out);
    } else {
        roi_pool_row_kernel_noperm<<<nw, 256, 0, stream>>>(fm, rois, nw, out);
    }
}

// Round 14
// 52.880 us; speedup vs baseline: 1.2292x; 1.2292x over previous
//
#include <hip/hip_runtime.h>

// RoiPoolingConv: fm [64,64,1024] f32 NHWC, rois [300,4] int32 (x,y,w,h),
// out [300,14,14,1024] f32.
//
// REPLICATE of the empirical-best config (R10 = 52.9 us; R13 same source =
// 65.0 us -> establishing the run-to-run noise band before declaring the
// roofline).
//  1. sort_items: counting-sort 4200 (roi,py) items by y0 into perm (d_ws).
//  2. roi_pool_cache_kernel: one block per item, 256 threads x float4 over
//     1024 channels, loop px. y0-sorted + bijective XCD swizzle (per-XCD L2
//     read locality). Plain per-px stores (NT stores: -6.5us, R8; NT loads:
//     -67us, R6). Monotone 2-column register cache with wave-uniform scalar
//     guards (R10: +1.1us).
// Structural roofline: 241 MB compulsory writes / 6.9 TB/s calibrated
// pure-store rate = 35 us; mixed read/write coexistence in L2/fabric adds
// ~1.4x, unresponsive to read-volume (x0.5), transactions (x0.55), latency
// pipelining, occupancy (x2), and cache-hint interventions (R4-R12).

#define POOL 14
#define FMW 64
#define CH 1024
#define C4 (CH / 4)        // 256 float4 per pixel
#define MAX_ITEMS (300 * POOL)

typedef float f4 __attribute__((ext_vector_type(4)));

__global__ __launch_bounds__(1024) void sort_items_kernel(
    const int* __restrict__ rois, int num_rois, int* __restrict__ perm)
{
    __shared__ int   base[64];
    __shared__ short s_y0[MAX_ITEMS];
    __shared__ int   s_yh[600];          // (y,h) per roi
    const int tid = threadIdx.x;
    const int num_items = num_rois * POOL;

    if (tid < 64) base[tid] = 0;
    for (int i = tid; i < num_rois; i += blockDim.x) {
        s_yh[i * 2]     = rois[i * 4 + 1];
        s_yh[i * 2 + 1] = rois[i * 4 + 3];
    }
    __syncthreads();

    for (int i = tid; i < num_items; i += blockDim.x) {
        const int roi = i / POOL, py = i % POOL;
        const int y = s_yh[roi * 2], h = s_yh[roi * 2 + 1];
        const float fy = (float)y + (float)py * ((float)h * (1.0f / 14.0f));
        const int y0 = (int)floorf(fy) & 63;
        s_y0[i] = (short)y0;
        atomicAdd(&base[y0], 1);
    }
    __syncthreads();

    if (tid < 64) {
        const int orig = base[tid];
        int v = orig;
        #pragma unroll
        for (int d = 1; d < 64; d <<= 1) {
            const int t = __shfl_up(v, d, 64);
            if (tid >= d) v += t;
        }
        base[tid] = v - orig;
    }
    __syncthreads();

    for (int i = tid; i < num_items; i += blockDim.x) {
        const int pos = atomicAdd(&base[(int)s_y0[i]], 1);
        perm[pos] = i;
    }
}

__global__ __launch_bounds__(256) void roi_pool_cache_kernel(
    const float* __restrict__ fm,
    const int* __restrict__ rois,
    const int* __restrict__ perm,
    int nw,
    float* __restrict__ out)
{
    // bijective XCD swizzle (nw % 8 == 0): XCD j gets a contiguous y0 band
    const int per = nw >> 3;
    const int b   = blockIdx.x;
    const int sb  = (b & 7) * per + (b >> 3);
    const int item = __builtin_amdgcn_readfirstlane(perm[sb]);

    const int py  = item % POOL;
    const int roi = item / POOL;

    const int4 r = *reinterpret_cast<const int4*>(rois + roi * 4);
    const int x = __builtin_amdgcn_readfirstlane(r.x);
    const int y = __builtin_amdgcn_readfirstlane(r.y);
    const int w = __builtin_amdgcn_readfirstlane(r.z);
    const int h = __builtin_amdgcn_readfirstlane(r.w);

    // Legacy-TF bilinear (align_corners=False, no half-pixel centers)
    const float fy = (float)y + (float)py * ((float)h * (1.0f / 14.0f));
    const int   y0 = __builtin_amdgcn_readfirstlane((int)floorf(fy));
    const int   y1 = min(y0 + 1, y + h - 1);
    const float wy = fy - (float)y0;

    const int c = threadIdx.x;  // float4 lane over channels
    const f4* row0 = reinterpret_cast<const f4*>(fm) + (size_t)(y0 * FMW) * C4 + c;
    const f4* row1 = reinterpret_cast<const f4*>(fm) + (size_t)(y1 * FMW) * C4 + c;
    f4* op = reinterpret_cast<f4*>(out) + (size_t)((roi * POOL + py) * POOL) * C4 + c;

    const float wscale = (float)w * (1.0f / 14.0f);
    const int   xmax   = x + w - 1;

    // 2-column register cache. Invariant: c1 == min(c0 + 1, xmax);
    // (tl,bl) hold column c0, (tr,br) hold column c1.
    int c0 = x;
    int c1 = min(x + 1, xmax);
    f4 tl = row0[(size_t)c0 * C4];
    f4 bl = row1[(size_t)c0 * C4];
    f4 tr, br;
    if (c1 != c0) { tr = row0[(size_t)c1 * C4]; br = row1[(size_t)c1 * C4]; }
    else          { tr = tl; br = bl; }

    for (int px = 0; px < POOL; ++px) {
        const float fx = (float)x + (float)px * wscale;
        const int   x0 = __builtin_amdgcn_readfirstlane((int)floorf(fx));
        const int   x1 = min(x0 + 1, xmax);
        const float wx = fx - (float)x0;

        if (x0 != c0) {
            if (x0 == c1) { tl = tr; bl = br; }       // shift left by one
            else { tl = row0[(size_t)x0 * C4]; bl = row1[(size_t)x0 * C4]; }
            c0 = x0;
            if (x1 != c1) {
                if (x1 == c0) { tr = tl; br = bl; }   // clamped at xmax
                else { tr = row0[(size_t)x1 * C4]; br = row1[(size_t)x1 * C4]; }
                c1 = x1;
            }
        }
        // else: x1 == min(x0+1,xmax) == c1 by invariant; cache fully valid

        const f4 top = tl + wx * (tr - tl);
        const f4 bot = bl + wx * (br - bl);
        const f4 o   = top + wy * (bot - top);
        op[(size_t)px * C4] = o;                      // plain streaming store
    }
}

// Fallback without permutation (identity order).
__global__ __launch_bounds__(256) void roi_pool_row_kernel_noperm(
    const float* __restrict__ fm,
    const int* __restrict__ rois,
    int nw,
    float* __restrict__ out)
{
    const int sb  = blockIdx.x;
    const int py  = sb % POOL;
    const int roi = sb / POOL;

    const int4 r = *reinterpret_cast<const int4*>(rois + roi * 4);
    const int x = r.x, y = r.y, w = r.z, h = r.w;

    const float fy = (float)y + (float)py * ((float)h * (1.0f / 14.0f));
    const int   y0 = (int)floorf(fy);
    const int   y1 = min(y0 + 1, y + h - 1);
    const float wy = fy - (float)y0;

    const int c = threadIdx.x;
    const f4* row0 = reinterpret_cast<const f4*>(fm) + (size_t)(y0 * FMW) * C4 + c;
    const f4* row1 = reinterpret_cast<const f4*>(fm) + (size_t)(y1 * FMW) * C4 + c;
    f4* op = reinterpret_cast<f4*>(out) + (size_t)((roi * POOL + py) * POOL) * C4 + c;

    const float wscale = (float)w * (1.0f / 14.0f);
    const int   xmax   = x + w - 1;

    for (int px = 0; px < POOL; ++px) {
        const float fx = (float)x + (float)px * wscale;
        const int   x0 = (int)floorf(fx);
        const int   x1 = min(x0 + 1, xmax);
        const float wx = fx - (float)x0;

        const f4 tl = row0[(size_t)x0 * C4];
        const f4 tr = row0[(size_t)x1 * C4];
        const f4 bl = row1[(size_t)x0 * C4];
        const f4 br = row1[(size_t)x1 * C4];

        const f4 top = tl + wx * (tr - tl);
        const f4 bot = bl + wx * (br - bl);
        const f4 o   = top + wy * (bot - top);

        op[(size_t)px * C4] = o;
    }
}

extern "C" void kernel_launch(void* const* d_in, const int* in_sizes, int n_in,
                              void* d_out, int out_size, void* d_ws, size_t ws_size,
                              hipStream_t stream) {
    const float* fm  = (const float*)d_in[0];   // [1,64,64,1024] f32
    const int* rois  = (const int*)d_in[1];     // [1,300,4] i32
    float* out       = (float*)d_out;           // [1,300,14,14,1024] f32

    const int num_rois = in_sizes[1] / 4;       // 300
    const int nw = num_rois * POOL;             // 4200 work items

    if (ws_size >= (size_t)nw * sizeof(int) && (nw & 7) == 0 && nw <= MAX_ITEMS) {
        int* perm = (int*)d_ws;
        sort_items_kernel<<<1, 1024, 0, stream>>>(rois, num_rois, perm);
        roi_pool_cache_kernel<<<nw, 256, 0, stream>>>(fm, rois, perm, nw, out);
    } else {
        roi_pool_row_kernel_noperm<<<nw, 256, 0, stream>>>(fm, rois, nw, out);
    }
}